// Round 4
// baseline (1184.715 us; speedup 1.0000x reference)
//
#include <hip/hip_runtime.h>

#define B_    4
#define N_    50000
#define E_    800000
#define FIN_  128
#define F_    64
#define BN_   (B_ * N_)        // 200000
#define TOT_  (BN_ * F_)       // 12,800,000
#define BE_   (B_ * E_)        // 3,200,000
#define ALPHA_ 0.2f
#define NEG_BIG_ -9.0e15f

#define XS_STRIDE 132

// ---- Kernel 1: h = X@W (fp32 -> d_out), e1/e2 = h@a1,h@a2 (fp32 -> ws) ----
__global__ __launch_bounds__(256) void gemm_kernel(
    const float* __restrict__ X,
    const float* __restrict__ W,
    const float* __restrict__ a,
    float* __restrict__ h_out,
    float* __restrict__ e1,
    float* __restrict__ e2) {
    __shared__ float Wf[FIN_ * F_];            // 32 KB
    __shared__ float Xs[64 * XS_STRIDE];       // 33.8 KB

    const int tid = threadIdx.x;

    const float4* Wg = (const float4*)W;
    for (int i = tid; i < 2048; i += 256)
        ((float4*)Wf)[i] = Wg[i];

    const int row0 = blockIdx.x * 64;
    const float4* Xg = (const float4*)(X + (size_t)row0 * FIN_);
    for (int i = tid; i < 2048; i += 256) {
        const int r = i >> 5;
        const int c = i & 31;
        float4 v = Xg[i];
        *(float4*)&Xs[r * XS_STRIDE + c * 4] = v;
    }
    __syncthreads();

    const int cg = tid & 15;
    const int rg = tid >> 4;

    float acc[4][4] = {};
#pragma unroll 4
    for (int k = 0; k < FIN_; ++k) {
        const float4 wv = *(const float4*)&Wf[k * F_ + cg * 4];
        float xr[4];
#pragma unroll
        for (int j = 0; j < 4; ++j)
            xr[j] = Xs[(rg * 4 + j) * XS_STRIDE + k];
#pragma unroll
        for (int j = 0; j < 4; ++j) {
            acc[j][0] += xr[j] * wv.x;
            acc[j][1] += xr[j] * wv.y;
            acc[j][2] += xr[j] * wv.z;
            acc[j][3] += xr[j] * wv.w;
        }
    }

    float a1v[4], a2v[4];
#pragma unroll
    for (int i = 0; i < 4; ++i) {
        a1v[i] = a[cg * 4 + i];
        a2v[i] = a[F_ + cg * 4 + i];
    }

#pragma unroll
    for (int j = 0; j < 4; ++j) {
        const int row = row0 + rg * 4 + j;
        float4 st = make_float4(acc[j][0], acc[j][1], acc[j][2], acc[j][3]);
        *(float4*)&h_out[(size_t)row * F_ + cg * 4] = st;

        float p1 = acc[j][0] * a1v[0] + acc[j][1] * a1v[1] +
                   acc[j][2] * a1v[2] + acc[j][3] * a1v[3];
        float p2 = acc[j][0] * a2v[0] + acc[j][1] * a2v[1] +
                   acc[j][2] * a2v[2] + acc[j][3] * a2v[3];
#pragma unroll
        for (int m = 8; m >= 1; m >>= 1) {
            p1 += __shfl_xor(p1, m);
            p2 += __shfl_xor(p2, m);
        }
        if (cg == 0) { e1[row] = p1; e2[row] = p2; }
    }
}

// ---- Kernel 2: count edges per src node (int histogram) ------------------
__global__ __launch_bounds__(256) void count_kernel(
    const int* __restrict__ edges, int* __restrict__ cnt) {
    const int g = blockIdx.x * 256 + threadIdx.x;   // grid exact: BE_/256
    const int b = g / E_;
    const int e = g - b * E_;
    const int s = edges[(size_t)b * 2 * E_ + e];
    atomicAdd(&cnt[b * N_ + s], 1);
}

// ---- Kernel 3: exclusive scan of cnt[BN] -> offs[BN+1], single block -----
#define SCAN_T 1024
#define SCAN_C 196    // ceil(BN/SCAN_T); 1024*196 = 200704 >= BN
__global__ __launch_bounds__(SCAN_T) void scan_kernel(
    const int* __restrict__ cnt, int* __restrict__ offs) {
    __shared__ int sums[SCAN_T];
    const int t = threadIdx.x;
    const int base = t * SCAN_C;

    int s = 0;
    for (int j = 0; j < SCAN_C; ++j) {
        const int i = base + j;
        if (i < BN_) s += cnt[i];
    }
    sums[t] = s;
    __syncthreads();
    for (int off = 1; off < SCAN_T; off <<= 1) {
        int v = (t >= off) ? sums[t - off] : 0;
        __syncthreads();
        sums[t] += v;
        __syncthreads();
    }
    int run = sums[t] - s;   // exclusive prefix for this strip
    for (int j = 0; j < SCAN_C; ++j) {
        const int i = base + j;
        if (i < BN_) { offs[i] = run; run += cnt[i]; }
    }
    if (t == SCAN_T - 1) offs[BN_] = run;   // == BE_
}

// ---- Kernel 4: place (dst, weight) into CSR slots ------------------------
__global__ __launch_bounds__(256) void place_kernel(
    const int* __restrict__ edges,
    const float* __restrict__ e1,
    const float* __restrict__ e2,
    const int* __restrict__ offs,
    int* __restrict__ cursor,
    int2* __restrict__ csr) {
    const int g = blockIdx.x * 256 + threadIdx.x;   // grid exact
    const int b = g / E_;
    const int e = g - b * E_;
    const int s = edges[(size_t)b * 2 * E_ + e];
    const int d = edges[(size_t)b * 2 * E_ + E_ + e];
    const int gs = b * N_ + s;
    const float sv = e1[gs] + e2[b * N_ + d];
    const float lr = sv > 0.0f ? sv : ALPHA_ * sv;
    const float wt = __expf(-lr);
    const int pos = offs[gs] + atomicAdd(&cursor[gs], 1);
    csr[pos] = make_int2(d, __float_as_int(wt));
}

// ---- Kernel 5: gather + normalize + elu, one wave per node ---------------
__global__ __launch_bounds__(256) void gather_kernel(
    const int* __restrict__ offs,     // global, indexed at b*N + s
    const int2* __restrict__ csr,
    const float* __restrict__ hb,     // batch-local h copy (N*64)
    float* __restrict__ outb,         // d_out + b*N*64
    int b) {
    const int lane = threadIdx.x & 63;
    const int s = (int)((blockIdx.x * 256 + threadIdx.x) >> 6);  // grid exact: N/4 blocks
    const int gs = b * N_ + s;
    const int k0 = offs[gs];
    const int k1 = offs[gs + 1];
    float acc = 0.0f, rs = 0.0f;
    for (int k = k0; k < k1; ++k) {
        const int2 r = csr[k];
        const float wt = __int_as_float(r.y);
        acc += wt * hb[(size_t)r.x * F_ + lane];
        rs += wt;
    }
    float v = acc / rs;
    if (v != v) v = NEG_BIG_;
    v = v > 0.0f ? v : (__expf(v) - 1.0f);
    outb[(size_t)s * F_ + lane] = v;
}

extern "C" void kernel_launch(void* const* d_in, const int* in_sizes, int n_in,
                              void* d_out, int out_size, void* d_ws, size_t ws_size,
                              hipStream_t stream) {
    const float* X = (const float*)d_in[0];
    const int* edges = (const int*)d_in[1];
    const float* W = (const float*)d_in[2];
    const float* a = (const float*)d_in[3];
    float* h = (float*)d_out;   // h (fp32) in d_out, overwritten per batch

    // ws layout (42.4 MB; round-3 proved >= 53.6 MB available):
    // [e1 BN][e2 BN][cnt BN][cursor BN][offs BN+2][csr BE int2][hb N*64]
    float* e1 = (float*)d_ws;
    float* e2 = e1 + BN_;
    int* cnt = (int*)(e2 + BN_);
    int* cursor = cnt + BN_;
    int* offs = cursor + BN_;
    int2* csr = (int2*)(offs + BN_ + 2);      // +2 keeps int2 8B-aligned
    float* hb = (float*)(csr + (size_t)BE_);

    hipMemsetAsync(cnt, 0, 2 * (size_t)BN_ * sizeof(int), stream);  // cnt+cursor

    gemm_kernel<<<BN_ / 64, 256, 0, stream>>>(X, W, a, h, e1, e2);
    count_kernel<<<BE_ / 256, 256, 0, stream>>>(edges, cnt);
    scan_kernel<<<1, SCAN_T, 0, stream>>>(cnt, offs);
    place_kernel<<<BE_ / 256, 256, 0, stream>>>(edges, e1, e2, offs, cursor, csr);

    for (int b = 0; b < B_; ++b) {
        hipMemcpyAsync(hb, h + (size_t)b * N_ * F_,
                       (size_t)N_ * F_ * sizeof(float),
                       hipMemcpyDeviceToDevice, stream);
        gather_kernel<<<(N_ * F_ / 64) / 4, 256, 0, stream>>>(
            offs, csr, hb, h + (size_t)b * N_ * F_, b);
    }
}

// Round 5
// 826.873 us; speedup vs baseline: 1.4328x; 1.4328x over previous
//
#include <hip/hip_runtime.h>

#define B_    4
#define N_    50000
#define E_    800000
#define FIN_  128
#define F_    64
#define BN_   (B_ * N_)        // 200000
#define TOT_  (BN_ * F_)       // 12,800,000
#define BE_   (B_ * E_)        // 3,200,000
#define ALPHA_ 0.2f
#define NEG_BIG_ -9.0e15f

#define XS_STRIDE 132

// ---- Kernel 1: h = X@W (fp32 -> d_out), e1/e2 = h@a1,h@a2 (fp32 -> ws) ----
__global__ __launch_bounds__(256) void gemm_kernel(
    const float* __restrict__ X,
    const float* __restrict__ W,
    const float* __restrict__ a,
    float* __restrict__ h_out,
    float* __restrict__ e1,
    float* __restrict__ e2) {
    __shared__ float Wf[FIN_ * F_];            // 32 KB
    __shared__ float Xs[64 * XS_STRIDE];       // 33.8 KB

    const int tid = threadIdx.x;

    const float4* Wg = (const float4*)W;
    for (int i = tid; i < 2048; i += 256)
        ((float4*)Wf)[i] = Wg[i];

    const int row0 = blockIdx.x * 64;
    const float4* Xg = (const float4*)(X + (size_t)row0 * FIN_);
    for (int i = tid; i < 2048; i += 256) {
        const int r = i >> 5;
        const int c = i & 31;
        float4 v = Xg[i];
        *(float4*)&Xs[r * XS_STRIDE + c * 4] = v;
    }
    __syncthreads();

    const int cg = tid & 15;
    const int rg = tid >> 4;

    float acc[4][4] = {};
#pragma unroll 4
    for (int k = 0; k < FIN_; ++k) {
        const float4 wv = *(const float4*)&Wf[k * F_ + cg * 4];
        float xr[4];
#pragma unroll
        for (int j = 0; j < 4; ++j)
            xr[j] = Xs[(rg * 4 + j) * XS_STRIDE + k];
#pragma unroll
        for (int j = 0; j < 4; ++j) {
            acc[j][0] += xr[j] * wv.x;
            acc[j][1] += xr[j] * wv.y;
            acc[j][2] += xr[j] * wv.z;
            acc[j][3] += xr[j] * wv.w;
        }
    }

    float a1v[4], a2v[4];
#pragma unroll
    for (int i = 0; i < 4; ++i) {
        a1v[i] = a[cg * 4 + i];
        a2v[i] = a[F_ + cg * 4 + i];
    }

#pragma unroll
    for (int j = 0; j < 4; ++j) {
        const int row = row0 + rg * 4 + j;
        float4 st = make_float4(acc[j][0], acc[j][1], acc[j][2], acc[j][3]);
        *(float4*)&h_out[(size_t)row * F_ + cg * 4] = st;

        float p1 = acc[j][0] * a1v[0] + acc[j][1] * a1v[1] +
                   acc[j][2] * a1v[2] + acc[j][3] * a1v[3];
        float p2 = acc[j][0] * a2v[0] + acc[j][1] * a2v[1] +
                   acc[j][2] * a2v[2] + acc[j][3] * a2v[3];
#pragma unroll
        for (int m = 8; m >= 1; m >>= 1) {
            p1 += __shfl_xor(p1, m);
            p2 += __shfl_xor(p2, m);
        }
        if (cg == 0) { e1[row] = p1; e2[row] = p2; }
    }
}

// ---- Kernel 2: count edges per src node (int histogram) ------------------
__global__ __launch_bounds__(256) void count_kernel(
    const int* __restrict__ edges, int* __restrict__ cnt) {
    const int g = blockIdx.x * 256 + threadIdx.x;   // grid exact: BE_/256
    const int b = g / E_;
    const int e = g - b * E_;
    const int s = edges[(size_t)b * 2 * E_ + e];
    atomicAdd(&cnt[b * N_ + s], 1);
}

// ---- 3-phase multi-block exclusive scan: cnt[BN] -> offs[BN+1] -----------
#define SB_ 196     // scan blocks
#define SE_ 1024    // elements per scan block; SB_*SE_ = 200704 >= BN_

__global__ __launch_bounds__(256) void scanA_kernel(
    const int* __restrict__ cnt, int* __restrict__ bsum) {
    __shared__ int red[256];
    const int t = threadIdx.x;
    const int base = blockIdx.x * SE_ + t * 4;
    int s = 0;
    if (base < BN_) {                       // BN_ % 4 == 0 -> full int4 ok
        const int4 v = *(const int4*)&cnt[base];
        s = v.x + v.y + v.z + v.w;
    }
    red[t] = s;
    __syncthreads();
    for (int off = 128; off >= 1; off >>= 1) {
        if (t < off) red[t] += red[t + off];
        __syncthreads();
    }
    if (t == 0) bsum[blockIdx.x] = red[0];
}

__global__ __launch_bounds__(256) void scanB_kernel(
    const int* __restrict__ bsum, int* __restrict__ boff,
    int* __restrict__ offs) {
    __shared__ int s[256];
    const int t = threadIdx.x;
    const int v = (t < SB_) ? bsum[t] : 0;
    s[t] = v;
    __syncthreads();
    for (int off = 1; off < 256; off <<= 1) {
        const int u = (t >= off) ? s[t - off] : 0;
        __syncthreads();
        s[t] += u;
        __syncthreads();
    }
    if (t < SB_) boff[t] = s[t] - v;        // exclusive block offset
    if (t == SB_ - 1) offs[BN_] = s[t];     // grand total == BE_
}

__global__ __launch_bounds__(256) void scanC_kernel(
    const int* __restrict__ cnt, const int* __restrict__ boff,
    int* __restrict__ offs) {
    __shared__ int s[256];
    const int t = threadIdx.x;
    const int base = blockIdx.x * SE_ + t * 4;
    int4 v = make_int4(0, 0, 0, 0);
    if (base < BN_) v = *(const int4*)&cnt[base];
    const int tot = v.x + v.y + v.z + v.w;
    s[t] = tot;
    __syncthreads();
    for (int off = 1; off < 256; off <<= 1) {
        const int u = (t >= off) ? s[t - off] : 0;
        __syncthreads();
        s[t] += u;
        __syncthreads();
    }
    if (base < BN_) {
        int run = boff[blockIdx.x] + s[t] - tot;   // exclusive
        int4 o;
        o.x = run;
        o.y = run + v.x;
        o.z = o.y + v.y;
        o.w = o.z + v.z;
        *(int4*)&offs[base] = o;
    }
}

// ---- Kernel 4: place (dst, weight) into CSR slots ------------------------
__global__ __launch_bounds__(256) void place_kernel(
    const int* __restrict__ edges,
    const float* __restrict__ e1,
    const float* __restrict__ e2,
    const int* __restrict__ offs,
    int* __restrict__ cursor,
    int2* __restrict__ csr) {
    const int g = blockIdx.x * 256 + threadIdx.x;   // grid exact
    const int b = g / E_;
    const int e = g - b * E_;
    const int s = edges[(size_t)b * 2 * E_ + e];
    const int d = edges[(size_t)b * 2 * E_ + E_ + e];
    const int gs = b * N_ + s;
    const float sv = e1[gs] + e2[b * N_ + d];
    const float lr = sv > 0.0f ? sv : ALPHA_ * sv;
    const float wt = __expf(-lr);
    const int pos = offs[gs] + atomicAdd(&cursor[gs], 1);
    csr[pos] = make_int2(d, __float_as_int(wt));
}

// ---- Kernel 5: gather + normalize + elu, one wave per node ---------------
__global__ __launch_bounds__(256) void gather_kernel(
    const int* __restrict__ offs,     // global, indexed at b*N + s
    const int2* __restrict__ csr,
    const float* __restrict__ hb,     // batch-local h copy (N*64)
    float* __restrict__ outb,         // d_out + b*N*64
    int b) {
    const int lane = threadIdx.x & 63;
    const int s = (int)((blockIdx.x * 256 + threadIdx.x) >> 6);  // grid exact
    const int gs = b * N_ + s;
    const int k0 = offs[gs];
    const int k1 = offs[gs + 1];
    float acc = 0.0f, rs = 0.0f;
    for (int k = k0; k < k1; ++k) {
        const int2 r = csr[k];
        const float wt = __int_as_float(r.y);
        acc += wt * hb[(size_t)r.x * F_ + lane];
        rs += wt;
    }
    float v = acc / rs;
    if (v != v) v = NEG_BIG_;
    v = v > 0.0f ? v : (__expf(v) - 1.0f);
    outb[(size_t)s * F_ + lane] = v;
}

extern "C" void kernel_launch(void* const* d_in, const int* in_sizes, int n_in,
                              void* d_out, int out_size, void* d_ws, size_t ws_size,
                              hipStream_t stream) {
    const float* X = (const float*)d_in[0];
    const int* edges = (const int*)d_in[1];
    const float* W = (const float*)d_in[2];
    const float* a = (const float*)d_in[3];
    float* h = (float*)d_out;   // h (fp32) in d_out, overwritten per batch

    // ws layout (~42.4 MB; round-3 proved >= 53.6 MB available):
    // [e1 BN][e2 BN][cnt BN][cursor BN][offs BN+2][bsum/boff 512][csr BE int2][hb N*64]
    float* e1 = (float*)d_ws;
    float* e2 = e1 + BN_;
    int* cnt = (int*)(e2 + BN_);
    int* cursor = cnt + BN_;
    int* offs = cursor + BN_;
    int* bsum = offs + BN_ + 2;               // 196 + pad
    int* boff = bsum + 256;
    int2* csr = (int2*)(boff + 256 + 2);      // 8B-aligned
    float* hb = (float*)(csr + (size_t)BE_);

    hipMemsetAsync(cnt, 0, 2 * (size_t)BN_ * sizeof(int), stream);  // cnt+cursor

    gemm_kernel<<<BN_ / 64, 256, 0, stream>>>(X, W, a, h, e1, e2);
    count_kernel<<<BE_ / 256, 256, 0, stream>>>(edges, cnt);
    scanA_kernel<<<SB_, 256, 0, stream>>>(cnt, bsum);
    scanB_kernel<<<1, 256, 0, stream>>>(bsum, boff, offs);
    scanC_kernel<<<SB_, 256, 0, stream>>>(cnt, boff, offs);
    place_kernel<<<BE_ / 256, 256, 0, stream>>>(edges, e1, e2, offs, cursor, csr);

    for (int b = 0; b < B_; ++b) {
        hipMemcpyAsync(hb, h + (size_t)b * N_ * F_,
                       (size_t)N_ * F_ * sizeof(float),
                       hipMemcpyDeviceToDevice, stream);
        gather_kernel<<<(N_ * F_ / 64) / 4, 256, 0, stream>>>(
            offs, csr, hb, h + (size_t)b * N_ * F_, b);
    }
}

// Round 6
// 669.648 us; speedup vs baseline: 1.7692x; 1.2348x over previous
//
#include <hip/hip_runtime.h>

#define B_    4
#define N_    50000
#define E_    800000
#define FIN_  128
#define F_    64
#define BN_   (B_ * N_)        // 200000
#define TOT_  (BN_ * F_)       // 12,800,000
#define BE_   (B_ * E_)        // 3,200,000
#define ALPHA_ 0.2f
#define NEG_BIG_ -9.0e15f

#define XS_STRIDE 132

__device__ __forceinline__ float bf2f(unsigned int u16) {
    union { unsigned int i; float f; } v;
    v.i = u16 << 16;
    return v.f;
}
__device__ __forceinline__ unsigned int f2bf(float f) {
    union { float f; unsigned int u; } v;
    v.f = f;
    unsigned int r = v.u + 0x7FFFu + ((v.u >> 16) & 1u);  // RNE
    return r >> 16;
}

// ---- Kernel 1: h = X@W (bf16 packed -> ws), e1/e2 (fp32 -> ws) ------------
__global__ __launch_bounds__(256) void gemm_kernel(
    const float* __restrict__ X,
    const float* __restrict__ W,
    const float* __restrict__ a,
    unsigned short* __restrict__ hq,
    float* __restrict__ e1,
    float* __restrict__ e2) {
    __shared__ float Wf[FIN_ * F_];            // 32 KB
    __shared__ float Xs[64 * XS_STRIDE];       // 33.8 KB

    const int tid = threadIdx.x;

    const float4* Wg = (const float4*)W;
    for (int i = tid; i < 2048; i += 256)
        ((float4*)Wf)[i] = Wg[i];

    const int row0 = blockIdx.x * 64;
    const float4* Xg = (const float4*)(X + (size_t)row0 * FIN_);
    for (int i = tid; i < 2048; i += 256) {
        const int r = i >> 5;
        const int c = i & 31;
        float4 v = Xg[i];
        *(float4*)&Xs[r * XS_STRIDE + c * 4] = v;
    }
    __syncthreads();

    const int cg = tid & 15;
    const int rg = tid >> 4;

    float acc[4][4] = {};
#pragma unroll 4
    for (int k = 0; k < FIN_; ++k) {
        const float4 wv = *(const float4*)&Wf[k * F_ + cg * 4];
        float xr[4];
#pragma unroll
        for (int j = 0; j < 4; ++j)
            xr[j] = Xs[(rg * 4 + j) * XS_STRIDE + k];
#pragma unroll
        for (int j = 0; j < 4; ++j) {
            acc[j][0] += xr[j] * wv.x;
            acc[j][1] += xr[j] * wv.y;
            acc[j][2] += xr[j] * wv.z;
            acc[j][3] += xr[j] * wv.w;
        }
    }

    float a1v[4], a2v[4];
#pragma unroll
    for (int i = 0; i < 4; ++i) {
        a1v[i] = a[cg * 4 + i];
        a2v[i] = a[F_ + cg * 4 + i];
    }

#pragma unroll
    for (int j = 0; j < 4; ++j) {
        const int row = row0 + rg * 4 + j;
        union { ushort4 v; unsigned short s[4]; } st;
#pragma unroll
        for (int i = 0; i < 4; ++i) st.s[i] = (unsigned short)f2bf(acc[j][i]);
        *(ushort4*)&hq[(size_t)row * F_ + cg * 4] = st.v;   // 8B-aligned

        float p1 = acc[j][0] * a1v[0] + acc[j][1] * a1v[1] +
                   acc[j][2] * a1v[2] + acc[j][3] * a1v[3];
        float p2 = acc[j][0] * a2v[0] + acc[j][1] * a2v[1] +
                   acc[j][2] * a2v[2] + acc[j][3] * a2v[3];
#pragma unroll
        for (int m = 8; m >= 1; m >>= 1) {
            p1 += __shfl_xor(p1, m);
            p2 += __shfl_xor(p2, m);
        }
        if (cg == 0) { e1[row] = p1; e2[row] = p2; }
    }
}

// ---- Kernel 2: count edges per src node ----------------------------------
__global__ __launch_bounds__(256) void count_kernel(
    const int* __restrict__ edges, int* __restrict__ cnt) {
    const int g = blockIdx.x * 256 + threadIdx.x;   // grid exact: BE_/256
    const int b = g / E_;
    const int e = g - b * E_;
    const int s = edges[(size_t)b * 2 * E_ + e];
    atomicAdd(&cnt[b * N_ + s], 1);
}

// ---- 3-phase multi-block exclusive scan: cnt[BN] -> offs[BN+1] -----------
#define SB_ 196
#define SE_ 1024

__global__ __launch_bounds__(256) void scanA_kernel(
    const int* __restrict__ cnt, int* __restrict__ bsum) {
    __shared__ int red[256];
    const int t = threadIdx.x;
    const int base = blockIdx.x * SE_ + t * 4;
    int s = 0;
    if (base < BN_) {
        const int4 v = *(const int4*)&cnt[base];
        s = v.x + v.y + v.z + v.w;
    }
    red[t] = s;
    __syncthreads();
    for (int off = 128; off >= 1; off >>= 1) {
        if (t < off) red[t] += red[t + off];
        __syncthreads();
    }
    if (t == 0) bsum[blockIdx.x] = red[0];
}

__global__ __launch_bounds__(256) void scanB_kernel(
    const int* __restrict__ bsum, int* __restrict__ boff,
    int* __restrict__ offs) {
    __shared__ int s[256];
    const int t = threadIdx.x;
    const int v = (t < SB_) ? bsum[t] : 0;
    s[t] = v;
    __syncthreads();
    for (int off = 1; off < 256; off <<= 1) {
        const int u = (t >= off) ? s[t - off] : 0;
        __syncthreads();
        s[t] += u;
        __syncthreads();
    }
    if (t < SB_) boff[t] = s[t] - v;
    if (t == SB_ - 1) offs[BN_] = s[t];
}

__global__ __launch_bounds__(256) void scanC_kernel(
    const int* __restrict__ cnt, const int* __restrict__ boff,
    int* __restrict__ offs) {
    __shared__ int s[256];
    const int t = threadIdx.x;
    const int base = blockIdx.x * SE_ + t * 4;
    int4 v = make_int4(0, 0, 0, 0);
    if (base < BN_) v = *(const int4*)&cnt[base];
    const int tot = v.x + v.y + v.z + v.w;
    s[t] = tot;
    __syncthreads();
    for (int off = 1; off < 256; off <<= 1) {
        const int u = (t >= off) ? s[t - off] : 0;
        __syncthreads();
        s[t] += u;
        __syncthreads();
    }
    if (base < BN_) {
        int run = boff[blockIdx.x] + s[t] - tot;
        int4 o;
        o.x = run;
        o.y = run + v.x;
        o.z = o.y + v.y;
        o.w = o.z + v.z;
        *(int4*)&offs[base] = o;
    }
}

// ---- Kernel 4: place (dst16 | wt_bf16) into CSR slots, one batch ---------
__global__ __launch_bounds__(256) void place_kernel(
    const int* __restrict__ edges,
    const float* __restrict__ e1,
    const float* __restrict__ e2,
    const int* __restrict__ offs,
    int* __restrict__ cursor,
    unsigned int* __restrict__ csr,
    int b) {
    const int e = blockIdx.x * 256 + threadIdx.x;   // grid exact: E_/256
    const int s = edges[(size_t)b * 2 * E_ + e];
    const int d = edges[(size_t)b * 2 * E_ + E_ + e];
    const int gs = b * N_ + s;
    const float sv = e1[gs] + e2[b * N_ + d];
    const float lr = sv > 0.0f ? sv : ALPHA_ * sv;
    const float wt = __expf(-lr);
    const int pos = offs[gs] + atomicAdd(&cursor[gs], 1);
    csr[pos] = (unsigned int)d | (f2bf(wt) << 16);
}

// ---- Kernel 5: gather + normalize + elu. Wave per node, 2 edges/iter. ----
__global__ __launch_bounds__(256) void gather_kernel(
    const int* __restrict__ offs,
    const unsigned int* __restrict__ csr,
    const unsigned int* __restrict__ hbu,   // batch h slice as packed pairs
    float* __restrict__ outb,               // d_out + b*N*64
    int b) {
    const int lane = threadIdx.x & 63;
    const int half = lane >> 5;
    const int sub = lane & 31;
    const int s = (int)((blockIdx.x * 256 + threadIdx.x) >> 6);  // grid exact
    const int gs = b * N_ + s;
    const int k0 = offs[gs];
    const int k1 = offs[gs + 1];
    float a0 = 0.0f, a1 = 0.0f, rs = 0.0f;
    for (int k = k0 + half; k < k1; k += 2) {
        const unsigned int ent = csr[k];
        const int d = (int)(ent & 0xFFFFu);
        const float wt = bf2f(ent >> 16);
        const unsigned int pk = hbu[(size_t)d * 32 + sub];
        a0 += wt * bf2f(pk & 0xFFFFu);
        a1 += wt * bf2f(pk >> 16);
        rs += wt;
    }
    a0 += __shfl_xor(a0, 32);
    a1 += __shfl_xor(a1, 32);
    rs += __shfl_xor(rs, 32);
    if (half == 0) {
        float v0 = a0 / rs, v1 = a1 / rs;
        if (v0 != v0) v0 = NEG_BIG_;
        if (v1 != v1) v1 = NEG_BIG_;
        v0 = v0 > 0.0f ? v0 : (__expf(v0) - 1.0f);
        v1 = v1 > 0.0f ? v1 : (__expf(v1) - 1.0f);
        *(float2*)&outb[(size_t)s * F_ + sub * 2] = make_float2(v0, v1);
    }
}

extern "C" void kernel_launch(void* const* d_in, const int* in_sizes, int n_in,
                              void* d_out, int out_size, void* d_ws, size_t ws_size,
                              hipStream_t stream) {
    const float* X = (const float*)d_in[0];
    const int* edges = (const int*)d_in[1];
    const float* W = (const float*)d_in[2];
    const float* a = (const float*)d_in[3];
    float* out = (float*)d_out;

    // ws layout (~47.2 MB, proven >= 53.6 MB available):
    // [e1 BN f32][e2 BN f32][hq BN*64 bf16][cnt BN][cursor BN][offs BN+2]
    // [bsum 256][boff 256][csr BE u32]
    float* e1 = (float*)d_ws;
    float* e2 = e1 + BN_;
    unsigned short* hq = (unsigned short*)(e2 + BN_);
    int* cnt = (int*)(hq + (size_t)BN_ * F_);
    int* cursor = cnt + BN_;
    int* offs = cursor + BN_;
    int* bsum = offs + BN_ + 2;
    int* boff = bsum + 256;
    unsigned int* csr = (unsigned int*)(boff + 256);

    hipMemsetAsync(cnt, 0, 2 * (size_t)BN_ * sizeof(int), stream);  // cnt+cursor

    gemm_kernel<<<BN_ / 64, 256, 0, stream>>>(X, W, a, hq, e1, e2);
    count_kernel<<<BE_ / 256, 256, 0, stream>>>(edges, cnt);
    scanA_kernel<<<SB_, 256, 0, stream>>>(cnt, bsum);
    scanB_kernel<<<1, 256, 0, stream>>>(bsum, boff, offs);
    scanC_kernel<<<SB_, 256, 0, stream>>>(cnt, boff, offs);

    for (int b = 0; b < B_; ++b) {
        place_kernel<<<E_ / 256, 256, 0, stream>>>(edges, e1, e2, offs, cursor, csr, b);
        gather_kernel<<<(N_ * F_ / 64) / 4, 256, 0, stream>>>(
            offs, csr, (const unsigned int*)(hq + (size_t)b * N_ * F_),
            out + (size_t)b * N_ * F_, b);
    }
}